// Round 9
// baseline (382.881 us; speedup 1.0000x reference)
//
#include <hip/hip_runtime.h>

#define IN_DIM 128
#define HID 256
#define OUTD 64
#define NB 256  // build blocks

typedef __attribute__((ext_vector_type(8))) short bf16x8;
typedef __attribute__((ext_vector_type(4))) float f32x4;
typedef __attribute__((ext_vector_type(2))) float f32x2;

// ---- bf16 helpers (RNE) ----
__device__ __forceinline__ unsigned short f2bf(float x) {
    unsigned int u = __float_as_uint(x);
    unsigned int r = (u + 0x7fffu + ((u >> 16) & 1u)) >> 16;
    return (unsigned short)r;
}
__device__ __forceinline__ float bf2f(unsigned short b) {
    return __uint_as_float(((unsigned int)b) << 16);
}
// unpack u32 holding 2 bf16 (lo = elem 2k, hi = elem 2k+1) -> f32x2
__device__ __forceinline__ f32x2 up2(unsigned int u) {
    f32x2 r;
    r.x = __uint_as_float(u << 16);
    r.y = __uint_as_float(u & 0xffff0000u);
    return r;
}

// ================= atomic-chain-free bucket-sort CSR build =================
// Buckets of 256 nodes: bucket(v) = v>>8. NBK = ceil(N/256) <= 512.
// part arrays layout: part[bucket * NB + block].

// Pass A: per-block LDS histograms over a chunk, written non-atomically.
// Also folds in the W1/W2 transpose+bf16 prep (independent work, spare threads).
__global__ __launch_bounds__(256) void k_bucketA(const int* __restrict__ src,
                                                 const int* __restrict__ dst,
                                                 int* __restrict__ partS, int* __restrict__ partD,
                                                 const float* __restrict__ W1, const float* __restrict__ W2,
                                                 unsigned short* __restrict__ Wt1,
                                                 unsigned short* __restrict__ Wt2,
                                                 int E, int NBK) {
    __shared__ int hS[512], hD[512];
    int b = blockIdx.x, t = threadIdx.x;
    // fold: W prep (one element per global thread)
    int g = b * 256 + t;
    if (g < IN_DIM * HID) {
        int k = g & (IN_DIM - 1), n = g >> 7;
        Wt1[(size_t)n * IN_DIM + k] = f2bf(W1[(size_t)k * HID + n]);
    }
    if (g < HID * OUTD) {
        int k = g & (HID - 1), n = g >> 8;
        Wt2[(size_t)n * HID + k] = f2bf(W2[(size_t)k * OUTD + n]);
    }
    for (int j = t; j < 512; j += 256) { hS[j] = 0; hD[j] = 0; }
    __syncthreads();
    int chunk = (E + NB - 1) / NB;
    int e0 = b * chunk, e1 = min(E, e0 + chunk);
    for (int e = e0 + t; e < e1; e += 256) {
        atomicAdd(&hS[src[e] >> 8], 1);
        atomicAdd(&hD[dst[e] >> 8], 1);
    }
    __syncthreads();
    for (int j = t; j < NBK; j += 256) {
        partS[j * NB + b] = hS[j];
        partD[j * NB + b] = hD[j];
    }
}

// Per-bucket parallel scan: exclusive relative prefix over the NB=256 per-block counts (in place),
// bucket totals out. One block per bucket.
__global__ __launch_bounds__(256) void k_bscanP(int* __restrict__ partS, int* __restrict__ partD,
                                                int* __restrict__ totS, int* __restrict__ totD) {
    __shared__ int sS[256], sD[256];
    int j = blockIdx.x, t = threadIdx.x;
    int vS = partS[j * NB + t], vD = partD[j * NB + t];
    sS[t] = vS; sD[t] = vD;
    __syncthreads();
    for (int o = 1; o < 256; o <<= 1) {
        int xS = (t >= o) ? sS[t - o] : 0;
        int xD = (t >= o) ? sD[t - o] : 0;
        __syncthreads();
        sS[t] += xS; sD[t] += xD;
        __syncthreads();
    }
    partS[j * NB + t] = sS[t] - vS;  // exclusive, bucket-relative
    partD[j * NB + t] = sD[t] - vD;
    if (t == 255) { totS[j] = sS[255]; totD[j] = sD[255]; }
}

// One-block scan over bucket totals only -> absolute bucket offsets.
__global__ __launch_bounds__(512) void k_bscanT(const int* __restrict__ totS,
                                                const int* __restrict__ totD,
                                                int* __restrict__ sOff, int* __restrict__ dOff,
                                                int* __restrict__ eoff,
                                                int N, int E, int NBK) {
    __shared__ int sS[512], sD[512];
    int t = threadIdx.x;
    int vS = (t < NBK) ? totS[t] : 0;
    int vD = (t < NBK) ? totD[t] : 0;
    sS[t] = vS; sD[t] = vD;
    __syncthreads();
    for (int o = 1; o < 512; o <<= 1) {
        int xS = (t >= o) ? sS[t - o] : 0;
        int xD = (t >= o) ? sD[t - o] : 0;
        __syncthreads();
        sS[t] += xS; sD[t] += xD;
        __syncthreads();
    }
    if (t < NBK) { sOff[t] = sS[t] - vS; dOff[t] = sD[t] - vD; }
    if (t == 0) { sOff[NBK] = E; dOff[NBK] = E; eoff[N] = E; }
}

// Pass B: place edges using per-block LDS cursors = relative prefix + bucket base. No global atomics.
__global__ __launch_bounds__(256) void k_bucketB2(const int* __restrict__ src,
                                                  const int* __restrict__ dst,
                                                  const int* __restrict__ partS,
                                                  const int* __restrict__ partD,
                                                  const int* __restrict__ sOff,
                                                  const int* __restrict__ dOff,
                                                  unsigned int* __restrict__ dpairs,
                                                  unsigned char* __restrict__ sloc,
                                                  int E, int NBK) {
    __shared__ int cS[512], cD[512];
    int b = blockIdx.x, t = threadIdx.x;
    for (int j = t; j < NBK; j += 256) {
        cS[j] = partS[j * NB + b] + sOff[j];
        cD[j] = partD[j * NB + b] + dOff[j];
    }
    __syncthreads();
    int chunk = (E + NB - 1) / NB;
    int e0 = b * chunk, e1 = min(E, e0 + chunk);
    for (int e = e0 + t; e < e1; e += 256) {
        int s = src[e], d = dst[e];
        int pD = atomicAdd(&cD[d >> 8], 1);
        dpairs[pD] = ((unsigned int)(d & 255) << 17) | (unsigned int)s;
        int pS = atomicAdd(&cS[s >> 8], 1);
        sloc[pS] = (unsigned char)(s & 255);
    }
}

// Pass C: per dst-bucket: fine histogram -> nd + eoff, then place esrc via LDS cursors.
__global__ __launch_bounds__(256) void k_bucketC(const unsigned int* __restrict__ dpairs,
                                                 const int* __restrict__ dOff,
                                                 int* __restrict__ eoff,
                                                 int* __restrict__ esrc,
                                                 float* __restrict__ nd,
                                                 int N) {
    __shared__ int hist[256], sc[256], cur[256];
    int b = blockIdx.x, t = threadIdx.x;
    int base = dOff[b], end = dOff[b + 1];
    hist[t] = 0;
    __syncthreads();
    for (int i = base + t; i < end; i += 256)
        atomicAdd(&hist[dpairs[i] >> 17], 1);
    __syncthreads();
    int cnt = hist[t];
    int v = b * 256 + t;
    if (v < N) nd[v] = rsqrtf((float)max(cnt, 1));
    sc[t] = cnt;
    __syncthreads();
    for (int o = 1; o < 256; o <<= 1) {
        int x = (t >= o) ? sc[t - o] : 0;
        __syncthreads();
        sc[t] += x;
        __syncthreads();
    }
    int excl = sc[t] - cnt;
    if (v < N) eoff[v] = base + excl;
    cur[t] = excl;
    __syncthreads();
    for (int i = base + t; i < end; i += 256) {
        unsigned int pk = dpairs[i];
        int pos = atomicAdd(&cur[pk >> 17], 1);
        esrc[base + pos] = (int)(pk & 0x1FFFFu);
    }
}

// Fused: per src-bucket fine histogram -> ns, then bf16-convert this bucket's h rows (hb = h*ns).
__global__ __launch_bounds__(256) void k_nsconv(const unsigned char* __restrict__ sloc,
                                                const int* __restrict__ sOff,
                                                const float* __restrict__ h,
                                                float* __restrict__ ns,
                                                unsigned short* __restrict__ hb,
                                                int N) {
    __shared__ int hist[256];
    __shared__ float nsf[256];
    int b = blockIdx.x, t = threadIdx.x;
    int base = sOff[b], end = sOff[b + 1];
    hist[t] = 0;
    __syncthreads();
    for (int i = base + t; i < end; i += 256)
        atomicAdd(&hist[sloc[i]], 1);
    __syncthreads();
    int v = b * 256 + t;
    float nsv = rsqrtf((float)max(hist[t], 1));
    nsf[t] = nsv;
    if (v < N) ns[v] = nsv;
    __syncthreads();
    // convert 256 rows x 32 float4
    int vb = b * 256;
    for (int idx = t; idx < 256 * 32; idx += 256) {
        int row = idx >> 5, col = idx & 31;
        if (vb + row < N) {
            float nv = nsf[row];
            float4 x = ((const float4*)h)[(size_t)(vb + row) * 32 + col];
            ushort4 o;
            o.x = f2bf(x.x * nv);
            o.y = f2bf(x.y * nv);
            o.z = f2bf(x.z * nv);
            o.w = f2bf(x.w * nv);
            ((ushort4*)hb)[(size_t)(vb + row) * 32 + col] = o;
        }
    }
}

// ---------------- SPMM1: bf16 gather of hb (pre-scaled), out xb bf16 [N][128] ----------------
// wave per node; 16 chunk-lanes x 4 edge-slots; 4-deep unroll -> 16 gathers in flight.
__global__ __launch_bounds__(256) void k_spmm1(const unsigned short* __restrict__ hb,
                                               const int* __restrict__ eoff,
                                               const int* __restrict__ esrc,
                                               const float* __restrict__ nd,
                                               unsigned short* __restrict__ xb, int N) {
    int wid = threadIdx.x >> 6;
    int v = blockIdx.x * 4 + wid;
    if (v >= N) return;
    int l = threadIdx.x & 63;
    int c = l & 15, el = l >> 4;
    int s0 = eoff[v], s1 = eoff[v + 1];

    f32x2 a0[4] = {}, a1[4] = {}, a2[4] = {}, a3[4] = {};
    int i = s0 + el;
    for (; i + 12 < s1; i += 16) {
        int sA = esrc[i], sB = esrc[i + 4], sC = esrc[i + 8], sD = esrc[i + 12];
        uint4 uA = *(const uint4*)(hb + (size_t)sA * IN_DIM + c * 8);
        uint4 uB = *(const uint4*)(hb + (size_t)sB * IN_DIM + c * 8);
        uint4 uC = *(const uint4*)(hb + (size_t)sC * IN_DIM + c * 8);
        uint4 uD = *(const uint4*)(hb + (size_t)sD * IN_DIM + c * 8);
        a0[0] += up2(uA.x); a0[1] += up2(uA.y); a0[2] += up2(uA.z); a0[3] += up2(uA.w);
        a1[0] += up2(uB.x); a1[1] += up2(uB.y); a1[2] += up2(uB.z); a1[3] += up2(uB.w);
        a2[0] += up2(uC.x); a2[1] += up2(uC.y); a2[2] += up2(uC.z); a2[3] += up2(uC.w);
        a3[0] += up2(uD.x); a3[1] += up2(uD.y); a3[2] += up2(uD.z); a3[3] += up2(uD.w);
    }
    for (; i < s1; i += 4) {
        int sA = esrc[i];
        uint4 uA = *(const uint4*)(hb + (size_t)sA * IN_DIM + c * 8);
        a0[0] += up2(uA.x); a0[1] += up2(uA.y); a0[2] += up2(uA.z); a0[3] += up2(uA.w);
    }
    float s[8];
#pragma unroll
    for (int j = 0; j < 4; ++j) {
        f32x2 tj = (a0[j] + a1[j]) + (a2[j] + a3[j]);
        float x0 = tj.x, x1 = tj.y;
        x0 += __shfl_xor(x0, 16); x0 += __shfl_xor(x0, 32);
        x1 += __shfl_xor(x1, 16); x1 += __shfl_xor(x1, 32);
        s[2 * j] = x0; s[2 * j + 1] = x1;
    }
    if (el == 0) {
        float ndv = nd[v];
        uint4 o;
        unsigned int* op = (unsigned int*)&o;
#pragma unroll
        for (int k = 0; k < 4; ++k) {
            unsigned int lo = f2bf(s[2 * k] * ndv);
            unsigned int hi = f2bf(s[2 * k + 1] * ndv);
            op[k] = lo | (hi << 16);
        }
        *(uint4*)(xb + (size_t)v * IN_DIM + c * 8) = o;
    }
}

// ---------------- MFMA GEMM: C = A(M x K,bf16) * Bt(BN x K,bf16)^T ----------------
template <int EPI>
__global__ __launch_bounds__(256) void k_mgemm(const unsigned short* __restrict__ A,
                                               const unsigned short* __restrict__ Bt,
                                               const float* __restrict__ b1,
                                               const float* __restrict__ p,
                                               const float* __restrict__ ns,
                                               unsigned short* __restrict__ outp,
                                               int M) {
    constexpr int BM = (EPI == 1) ? 64 : 256;
    constexpr int BN = (EPI == 1) ? 256 : 64;
    constexpr int K = (EPI == 1) ? 128 : 256;
    constexpr int OUT_LD = (EPI == 1) ? 256 : 64;
    __shared__ unsigned short As[BM * 64];
    __shared__ unsigned short Bs[BN * 64];
    const int t = threadIdx.x, w = t >> 6, l = t & 63;
    const int row0 = blockIdx.x * BM;
    const int wm0 = (EPI == 1) ? 0 : w * 64;
    const int wn0 = (EPI == 1) ? w * 64 : 0;
    const int lr = l & 15, lk = (l >> 4) * 8, lg = l >> 4;

    f32x4 acc[4][4] = {};

    for (int k0 = 0; k0 < K; k0 += 64) {
#pragma unroll
        for (int q = 0; q < BM / 32; ++q) {
            int chunk = w * (BM / 32) + q;
            int gr = row0 + chunk * 8 + (l >> 3);
            if (gr > M - 1) gr = M - 1;
            const unsigned short* gp = A + (size_t)gr * K + k0 + (l & 7) * 8;
            __builtin_amdgcn_global_load_lds((const __attribute__((address_space(1))) void*)gp,
                                             (__attribute__((address_space(3))) void*)&As[chunk * 512], 16, 0, 0);
        }
#pragma unroll
        for (int q = 0; q < BN / 32; ++q) {
            int chunk = w * (BN / 32) + q;
            int r = chunk * 8 + (l >> 3);
            const unsigned short* gp = Bt + (size_t)r * K + k0 + (l & 7) * 8;
            __builtin_amdgcn_global_load_lds((const __attribute__((address_space(1))) void*)gp,
                                             (__attribute__((address_space(3))) void*)&Bs[chunk * 512], 16, 0, 0);
        }
        __syncthreads();

#pragma unroll
        for (int kk = 0; kk < 2; ++kk) {
            bf16x8 a[4], b[4];
#pragma unroll
            for (int m = 0; m < 4; ++m)
                a[m] = *(const bf16x8*)&As[(wm0 + m * 16 + lr) * 64 + kk * 32 + lk];
#pragma unroll
            for (int n = 0; n < 4; ++n)
                b[n] = *(const bf16x8*)&Bs[(wn0 + n * 16 + lr) * 64 + kk * 32 + lk];
#pragma unroll
            for (int m = 0; m < 4; ++m)
#pragma unroll
                for (int n = 0; n < 4; ++n)
                    acc[m][n] = __builtin_amdgcn_mfma_f32_16x16x32_bf16(a[m], b[n], acc[m][n], 0, 0, 0);
        }
        __syncthreads();
    }

#pragma unroll
    for (int n = 0; n < 4; ++n) {
        int col = wn0 + n * 16 + lr;
        float bb = 0.f, pp = 1.f;
        if (EPI == 1) {
            bb = b1[col];
            pp = fminf(fmaxf(p[col], 0.f), 1.f);
        }
#pragma unroll
        for (int m = 0; m < 4; ++m) {
#pragma unroll
            for (int j = 0; j < 4; ++j) {
                int row = row0 + wm0 + m * 16 + lg * 4 + j;
                if (row < M) {
                    float v = acc[m][n][j];
                    if (EPI == 1) {
                        v = fmaxf(v + bb, 0.f) * pp;
                    } else {
                        v *= ns[row];
                    }
                    outp[(size_t)row * OUT_LD + col] = f2bf(v);
                }
            }
        }
    }
}

// ---------------- SPMM2: bf16 gather of y, out fp32 ----------------
// wave per node; 16 chunk-lanes x 4 edge-slots; 4-deep unroll -> 16 gathers in flight.
__global__ __launch_bounds__(256) void k_spmm2(const unsigned short* __restrict__ ybf,
                                               const int* __restrict__ eoff,
                                               const int* __restrict__ esrc,
                                               const float* __restrict__ nd,
                                               const float* __restrict__ b2,
                                               float* __restrict__ out, int N) {
    int wid = threadIdx.x >> 6;
    int v = blockIdx.x * 4 + wid;
    if (v >= N) return;
    int l = threadIdx.x & 63;
    int c = l & 15, el = l >> 4;
    int s0 = eoff[v], s1 = eoff[v + 1];

    f32x2 q0[2] = {}, q1[2] = {}, q2[2] = {}, q3[2] = {};
    int i = s0 + el;
    for (; i + 12 < s1; i += 16) {
        int sA = esrc[i], sB = esrc[i + 4], sC = esrc[i + 8], sD = esrc[i + 12];
        uint2 uA = *(const uint2*)(ybf + (size_t)sA * OUTD + c * 4);
        uint2 uB = *(const uint2*)(ybf + (size_t)sB * OUTD + c * 4);
        uint2 uC = *(const uint2*)(ybf + (size_t)sC * OUTD + c * 4);
        uint2 uD = *(const uint2*)(ybf + (size_t)sD * OUTD + c * 4);
        q0[0] += up2(uA.x); q0[1] += up2(uA.y);
        q1[0] += up2(uB.x); q1[1] += up2(uB.y);
        q2[0] += up2(uC.x); q2[1] += up2(uC.y);
        q3[0] += up2(uD.x); q3[1] += up2(uD.y);
    }
    for (; i < s1; i += 4) {
        uint2 u = *(const uint2*)(ybf + (size_t)esrc[i] * OUTD + c * 4);
        q0[0] += up2(u.x); q0[1] += up2(u.y);
    }
    f32x2 t0 = (q0[0] + q1[0]) + (q2[0] + q3[0]);
    f32x2 t1 = (q0[1] + q1[1]) + (q2[1] + q3[1]);
    float ax = t0.x, ay = t0.y, az = t1.x, aw = t1.y;
    ax += __shfl_xor(ax, 16); ax += __shfl_xor(ax, 32);
    ay += __shfl_xor(ay, 16); ay += __shfl_xor(ay, 32);
    az += __shfl_xor(az, 16); az += __shfl_xor(az, 32);
    aw += __shfl_xor(aw, 16); aw += __shfl_xor(aw, 32);
    if (l < 16) {
        float ndv = nd[v];
        float4 bb = *(const float4*)(b2 + c * 4);
        float4 o;
        o.x = ax * ndv + bb.x;
        o.y = ay * ndv + bb.y;
        o.z = az * ndv + bb.z;
        o.w = aw * ndv + bb.w;
        *(float4*)(out + (size_t)v * OUTD + c * 4) = o;
    }
}

extern "C" void kernel_launch(void* const* d_in, const int* in_sizes, int n_in,
                              void* d_out, int out_size, void* d_ws, size_t ws_size,
                              hipStream_t stream) {
    const float* h  = (const float*)d_in[0];
    const float* W1 = (const float*)d_in[1];
    const float* b1 = (const float*)d_in[2];
    const float* W2 = (const float*)d_in[3];
    const float* b2 = (const float*)d_in[4];
    const float* p  = (const float*)d_in[5];
    const int* src  = (const int*)d_in[6];
    const int* dst  = (const int*)d_in[7];

    const int N = in_sizes[0] / IN_DIM;
    const int E = in_sizes[6];
    const int NBK = (N + 255) >> 8;  // 391 for N=100000 (<= 512)
    float* out = (float*)d_out;

    char* ws = (char*)d_ws;
    size_t off = 0;
    auto alloc = [&](size_t bytes) -> void* {
        void* ptr = ws + off;
        off = (off + bytes + 255) & ~(size_t)255;
        return ptr;
    };
    int* sOff = (int*)alloc(513 * 4);
    int* dOff = (int*)alloc(513 * 4);
    int* totS = (int*)alloc(512 * 4);
    int* totD = (int*)alloc(512 * 4);
    int* eoff = (int*)alloc((size_t)(N + 1) * 4);
    int* esrc = (int*)alloc((size_t)E * 4);
    float* ns = (float*)alloc((size_t)N * 4);
    float* nd = (float*)alloc((size_t)N * 4);
    unsigned short* hb  = (unsigned short*)alloc((size_t)N * IN_DIM * 2);  // 25.6 MB
    unsigned short* xb  = (unsigned short*)alloc((size_t)N * IN_DIM * 2);  // 25.6 MB
    unsigned short* hid = (unsigned short*)alloc((size_t)N * HID * 2);     // 51.2 MB
    unsigned short* Wt1 = (unsigned short*)alloc((size_t)HID * IN_DIM * 2);
    unsigned short* Wt2 = (unsigned short*)alloc((size_t)OUTD * HID * 2);
    unsigned short* ybf = xb;  // xb dead after GEMM1
    // build-time overlays in the hid region (dead until GEMM1 writes it)
    unsigned int* dpairs = (unsigned int*)hid;                             // E*4 = 6.4 MB
    unsigned char* sloc  = (unsigned char*)hid + (size_t)E * 4;            // E*1 = 1.6 MB
    int* partS = (int*)((char*)hid + ((size_t)E * 5 + 255 & ~(size_t)255)); // 512KB
    int* partD = partS + 512 * NB;                                          // 512KB

    k_bucketA<<<NB, 256, 0, stream>>>(src, dst, partS, partD, W1, W2, Wt1, Wt2, E, NBK);
    k_bscanP<<<NBK, 256, 0, stream>>>(partS, partD, totS, totD);
    k_bscanT<<<1, 512, 0, stream>>>(totS, totD, sOff, dOff, eoff, N, E, NBK);
    k_bucketB2<<<NB, 256, 0, stream>>>(src, dst, partS, partD, sOff, dOff, dpairs, sloc, E, NBK);
    k_bucketC<<<NBK, 256, 0, stream>>>(dpairs, dOff, eoff, esrc, nd, N);
    k_nsconv<<<NBK, 256, 0, stream>>>(sloc, sOff, h, ns, hb, N);

    k_spmm1<<<(N + 3) / 4, 256, 0, stream>>>(hb, eoff, esrc, nd, xb, N);

    k_mgemm<1><<<(N + 63) / 64, 256, 0, stream>>>(xb, Wt1, b1, p, nullptr, hid, N);

    k_mgemm<2><<<(N + 255) / 256, 256, 0, stream>>>(hid, Wt2, nullptr, nullptr, ns, ybf, N);

    k_spmm2<<<(N + 3) / 4, 256, 0, stream>>>(ybf, eoff, esrc, nd, b2, out, N);
}